// Round 7
// baseline (376.534 us; speedup 1.0000x reference)
//
#include <hip/hip_runtime.h>

// Chamfer NN squared distance, both directions. B=8, N=M=16384, D=3, fp32.
// VALU path (MFMA abandoned after 3 rounds of un-diagnosable failures).
//
// dist(x_i) = sx_i + min_j (sy_j - 2 x_i . y_j)
// y staged in LDS as float4 {x,y,z,|y|^2}; inner op = 3 scalar FMA per pair
// + v_min3 folding 2 y-points per instr, amortized over PPT=8 queries.
// y-range split NSEG=8 ways; per-segment partial minima written to d_ws
// planes (no atomics), folded by a second reduce kernel. Atomic variant
// (template) is the fallback if ws_size is too small.

#define NB      8
#define NPTS    16384
#define THREADS 256
#define PPT     8
#define QPB     (THREADS * PPT)        // 2048 queries per block
#define CHUNKS  (NPTS / QPB)           // 8
#define NSEG    8
#define YSEG    (NPTS / NSEG)          // 2048
#define TILE    1024                   // y points per LDS tile (16 KB)
#define TOTQ    (2 * NB * NPTS)        // 262144 total outputs

__device__ __forceinline__ float min3f(float a, float b, float c) {
    float d;
    asm("v_min3_f32 %0, %1, %2, %3" : "=v"(d) : "v"(a), "v"(b), "v"(c));
    return d;
}

template<int ATOMIC>
__global__ __launch_bounds__(THREADS, 4)
void nnd_main(const float* __restrict__ x1, const float* __restrict__ x2,
              float* __restrict__ dst)
{
    // grid = 2 * NB * CHUNKS * NSEG = 1024
    const int bid   = blockIdx.x;
    const int seg   = bid & (NSEG - 1);
    const int rem1  = bid >> 3;
    const int chunk = rem1 & (CHUNKS - 1);
    const int rem2  = rem1 >> 3;
    const int batch = rem2 & (NB - 1);
    const int dir   = rem2 >> 3;

    const float* __restrict__ xb = (dir ? x2 : x1) + (size_t)batch * NPTS * 3;
    const float* __restrict__ yb = (dir ? x1 : x2) + (size_t)batch * NPTS * 3;

    // ATOMIC: dst = out (merge via atomicMin). Else: dst = partial plane[seg].
    float* __restrict__ po = dst
        + (ATOMIC ? (size_t)0 : (size_t)seg * TOTQ)
        + (size_t)dir * NB * NPTS + (size_t)batch * NPTS + (size_t)chunk * QPB;

    __shared__ float4 yt[TILE];

    const int t = threadIdx.x;

    float nx[PPT], ny[PPT], nz[PPT], sx[PPT], ac[PPT];
#pragma unroll
    for (int p = 0; p < PPT; ++p) {
        const int q = chunk * QPB + t + p * THREADS;
        const float X = xb[3 * q + 0], Y = xb[3 * q + 1], Z = xb[3 * q + 2];
        sx[p] = fmaf(X, X, fmaf(Y, Y, Z * Z));
        nx[p] = -2.0f * X;
        ny[p] = -2.0f * Y;
        nz[p] = -2.0f * Z;
        ac[p] = INFINITY;
    }

    const int ybeg = seg * YSEG;
    for (int tb = ybeg; tb < ybeg + YSEG; tb += TILE) {
        // stage TILE y points as {x,y,z,|y|^2}
#pragma unroll
        for (int s = 0; s < TILE / THREADS; ++s) {
            const int k = t + s * THREADS;
            const float* yp = yb + 3 * (size_t)(tb + k);
            const float a = yp[0], b = yp[1], c = yp[2];
            yt[k] = make_float4(a, b, c, fmaf(a, a, fmaf(b, b, c * c)));
        }
        __syncthreads();

#pragma unroll 2
        for (int j = 0; j < TILE; j += 2) {
            const float4 p0 = yt[j];       // uniform address -> LDS broadcast
            const float4 p1 = yt[j + 1];
#pragma unroll
            for (int p = 0; p < PPT; ++p) {
                const float d0 = fmaf(nx[p], p0.x, fmaf(ny[p], p0.y, fmaf(nz[p], p0.z, p0.w)));
                const float d1 = fmaf(nx[p], p1.x, fmaf(ny[p], p1.y, fmaf(nz[p], p1.z, p1.w)));
                ac[p] = min3f(d0, d1, ac[p]);
            }
        }
        __syncthreads();
    }

#pragma unroll
    for (int p = 0; p < PPT; ++p) {
        const float v = sx[p] + ac[p];
        if (ATOMIC) {
            const float vc = fmaxf(v, 0.0f);  // keep uint-bit ordering valid
            atomicMin((unsigned int*)&po[t + p * THREADS], __float_as_uint(vc));
        } else {
            po[t + p * THREADS] = v;
        }
    }
}

__global__ __launch_bounds__(THREADS)
void nnd_reduce(const float* __restrict__ part, float* __restrict__ out)
{
    const int i = blockIdx.x * THREADS + threadIdx.x;   // 0..TOTQ-1
    float m = part[i];
#pragma unroll
    for (int s = 1; s < NSEG; ++s)
        m = fminf(m, part[(size_t)s * TOTQ + i]);
    out[i] = m;
}

extern "C" void kernel_launch(void* const* d_in, const int* in_sizes, int n_in,
                              void* d_out, int out_size, void* d_ws, size_t ws_size,
                              hipStream_t stream) {
    const float* x1 = (const float*)d_in[0];
    const float* x2 = (const float*)d_in[1];
    float* out = (float*)d_out;

    constexpr int grid = 2 * NB * CHUNKS * NSEG;           // 1024
    const size_t part_bytes = (size_t)NSEG * TOTQ * 4;     // 8 MiB

    if (ws_size >= part_bytes) {
        float* part = (float*)d_ws;
        nnd_main<0><<<dim3(grid), dim3(THREADS), 0, stream>>>(x1, x2, part);
        nnd_reduce<<<dim3(TOTQ / THREADS), dim3(THREADS), 0, stream>>>(part, out);
    } else {
        hipMemsetAsync(out, 0xFF, (size_t)out_size * sizeof(float), stream);
        nnd_main<1><<<dim3(grid), dim3(THREADS), 0, stream>>>(x1, x2, out);
    }
}